// Round 5
// baseline (916.331 us; speedup 1.0000x reference)
//
#include <hip/hip_runtime.h>

// HPCrnn R5: R3 block-coop structure + i8 MFMA weights in REGISTERS (zero LDS
// weight traffic, R4's killer) + parity-staggered phases (fix R3's MFMA/VALU
// serialization: waves 0-3 do {gemm;epi}, waves 4-7 do {epi;gemm} -> each SIMD
// (hosting wave i and i+4) keeps matrix AND vector pipes busy every phase).
// i8 16x16x64 MFMA: weights 64 VGPRs total. Stages (q(ec3),q(ca1)) i8 in LDS,
// XOR-swizzled (2-way max bank aliasing = free). Per-step tables A=basal*cq,
// E=(basal-bias)*cq+0.5 prefetched from global one step ahead.

typedef int   i32x4 __attribute__((ext_vector_type(4)));
typedef float f32x4 __attribute__((ext_vector_type(4)));

// ---------- pre 1: basal tables (natural feature order) + zero scale slots ----------
__global__ void basal2_kernel(const float* __restrict__ Wbasal,
                              const float* __restrict__ bias,
                              float* __restrict__ Atab, float* __restrict__ Etab,
                              float* __restrict__ ctab, int* __restrict__ scaleWS) {
    const int t = blockIdx.x, n = threadIdx.x;
    __shared__ float ca3s[256], red[256];
    const float x = (float)(t + 1);
    const float c0 = (float)n * (100.0f / 255.0f);
    const float d = (x - c0) * 0.2f;
    ca3s[n] = expf(-0.5f * d * d);
    __syncthreads();
    float bas = 0.f;
    #pragma unroll 8
    for (int k = 0; k < 256; ++k) bas += ca3s[k] * Wbasal[k * 256 + n];
    red[n] = bas;
    __syncthreads();
    for (int s = 128; s > 0; s >>= 1) {
        if (n < s) red[n] = fmaxf(red[n], red[n + s]);
        __syncthreads();
    }
    const float bmax = red[0];
    const float cq = 126.0f / (2.0f * bmax);   // 126: headroom so q(ca1) < 127.5
    Atab[t * 256 + n] = bas * cq;
    Etab[t * 256 + n] = (bas - bias[n]) * cq + 0.5f;   // +0.5 folds rounding
    if (n == 0) ctab[t] = (2.0f * bmax) / 126.0f;
    if (t == 0 && n < 2) scaleWS[n] = 0;
}

// ---------- pre 2: weight absmax (atomicMax on positive float bits) ----------
__global__ void wmax_kernel(const float* __restrict__ Wap, const float* __restrict__ Wc,
                            int* __restrict__ scaleWS) {
    const int i = blockIdx.x * 256 + threadIdx.x;
    float m1 = fabsf(Wap[i]);
    float m2 = fabsf(Wc[i]);
    #pragma unroll
    for (int o = 1; o < 64; o <<= 1) {
        m1 = fmaxf(m1, __shfl_xor(m1, o));
        m2 = fmaxf(m2, __shfl_xor(m2, o));
    }
    __shared__ float r1[4], r2[4];
    const int wv = threadIdx.x >> 6, ln = threadIdx.x & 63;
    if (ln == 0) { r1[wv] = m1; r2[wv] = m2; }
    __syncthreads();
    if (threadIdx.x == 0) {
        const float a = fmaxf(fmaxf(r1[0], r1[1]), fmaxf(r1[2], r1[3]));
        const float b = fmaxf(fmaxf(r2[0], r2[1]), fmaxf(r2[2], r2[3]));
        atomicMax(&scaleWS[0], __float_as_int(a));
        atomicMax(&scaleWS[1], __float_as_int(b));
    }
}

// ---------- pre 3: quantize weights to i8, transposed to [m][k] ----------
__global__ void wquant_kernel(const float* __restrict__ Wap, const float* __restrict__ Wc,
                              const int* __restrict__ scaleWS,
                              char* __restrict__ qWap, char* __restrict__ qWc) {
    const int m = blockIdx.x, k = threadIdx.x;
    const float q1 = 127.0f / __int_as_float(scaleWS[0]);
    const float q2 = 127.0f / __int_as_float(scaleWS[1]);
    qWap[m * 256 + k] = (char)(int)rintf(Wap[k * 256 + m] * q1);
    qWc[m * 256 + k]  = (char)(int)rintf(Wc[k * 256 + m] * q2);
}

// ---------- main: 32 rows/block, dual 16-row tiles, staggered phases ----------
__global__ __launch_bounds__(512, 2) void rnn_kernel(
    const float* __restrict__ cue, const float* __restrict__ ec5_init,
    const char* __restrict__ qWap, const char* __restrict__ qWc,
    const int* __restrict__ scaleWS, const float* __restrict__ Wact,
    const float* __restrict__ Atab, const float* __restrict__ Etab,
    const float* __restrict__ ctab, float* __restrict__ out)
{
    __shared__ __align__(16) char sStage[16384];  // EA@0 CA@4096 EB@8192 CB@12288
    __shared__ float sPart[512];                  // [row(0..31)][a][wave]

    const int tid  = threadIdx.x;
    const int wave = tid >> 6;
    const int lane = tid & 63;
    const int quad = lane >> 4;
    const int L    = lane & 15;
    const int wb   = wave * 32;
    const int row0 = blockIdx.x * 32;
    const bool wlow = wave < 4;   // SIMD i hosts waves i, i+4 -> one of each order

    const float sW1 = __int_as_float(scaleWS[0]);
    const float sW2 = __int_as_float(scaleWS[1]);
    const float nf1 = -sW1 / (127.0f * 127.0f);   // gemm1 dequant (ec3 scale 127)
    const float sWc127 = sW2 / 127.0f;

    // weight A-frags: lane (quad,L) holds W^T[m=wb+mt*16+L][k=c*64+quad*16+j]
    i32x4 WA[2][4], WC[2][4];
    #pragma unroll
    for (int mt = 0; mt < 2; ++mt) {
        const int m = wb + mt * 16 + L;
        #pragma unroll
        for (int c = 0; c < 4; ++c) {
            WA[mt][c] = *(const i32x4*)&qWap[m * 256 + c * 64 + quad * 16];
            WC[mt][c] = *(const i32x4*)&qWc[m * 256 + c * 64 + quad * 16];
        }
    }

    // state fp32 (C/D layout): lane (quad,L) holds rows {L, 16+L}, feats wb+mt*16+quad*4+r
    float e5A[2][4], e3A[2][4], e5B[2][4], e3B[2][4];
    #pragma unroll
    for (int mt = 0; mt < 2; ++mt) {
        const int f0 = wb + mt * 16 + quad * 4;
        const f32x4 a = *(const f32x4*)&ec5_init[(row0 + L) * 256 + f0];
        const f32x4 b = *(const f32x4*)&ec5_init[(row0 + 16 + L) * 256 + f0];
        #pragma unroll
        for (int r = 0; r < 4; ++r) {
            e5A[mt][r] = a[r]; e5B[mt][r] = b[r];
            e3A[mt][r] = 0.f;  e3B[mt][r] = 0.f;
        }
    }

    // XOR-swizzled stage addresses (16-B blocks xor'd with row L): 2-way max conflicts
    int rd[4], wr[2];
    #pragma unroll
    for (int c = 0; c < 4; ++c)
        rd[c] = L * 256 + (((4 * c + quad) ^ L) << 4);
    #pragma unroll
    for (int mt = 0; mt < 2; ++mt)
        wr[mt] = L * 256 + (((wave * 2 + mt) ^ L) << 4) + quad * 4;

    auto gemm = [&](int sb, const i32x4 (&W)[2][4], i32x4 (&acc)[2]) {
        #pragma unroll
        for (int c = 0; c < 4; ++c) {
            const i32x4 bf = *(const i32x4*)&sStage[sb + rd[c]];
            acc[0] = __builtin_amdgcn_mfma_i32_16x16x64_i8(W[0][c], bf, acc[0], 0, 0, 0);
            acc[1] = __builtin_amdgcn_mfma_i32_16x16x64_i8(W[1][c], bf, acc[1], 0, 0, 0);
        }
    };
    auto e1 = [&](const i32x4 (&acc)[2], const f32x4 (&av)[2], const f32x4 (&ev)[2], int sb) {
        #pragma unroll
        for (int mt = 0; mt < 2; ++mt) {
            unsigned dw = 0;
            #pragma unroll
            for (int r = 0; r < 4; ++r) {
                const float xf = (float)acc[mt][r];
                const float s  = __builtin_amdgcn_rcpf(1.0f + __expf(xf * nf1));
                const float v  = fmaxf(fmaf(av[mt][r], s, ev[mt][r]), 0.0f);
                dw |= ((unsigned)v) << (8 * r);
            }
            *(unsigned*)&sStage[sb + wr[mt]] = dw;
        }
    };
    auto e2 = [&](const i32x4 (&acc)[2], float (&e5)[2][4], float (&e3)[2][4],
                  int sb, float f2) {
        #pragma unroll
        for (int mt = 0; mt < 2; ++mt) {
            unsigned dw = 0;
            #pragma unroll
            for (int r = 0; r < 4; ++r) {
                const float n5 = __builtin_amdgcn_fmed3f(
                    fmaf((float)acc[mt][r], f2, e5[mt][r]), 0.0f, 1.0f);
                const float n3 = n5 * e3[mt][r];   // both in [0,1]: clip redundant
                e5[mt][r] = n5; e3[mt][r] = n3;
                dw |= ((unsigned)fmaf(n3, 127.0f, 0.5f)) << (8 * r);
            }
            *(unsigned*)&sStage[sb + wr[mt]] = dw;
        }
    };

    // ===== t = 0 (peeled): ec3=0 -> sigmoid = 0.5 exactly; ca1 row-independent =====
    f32x4 avc[2], evc[2];
    #pragma unroll
    for (int mt = 0; mt < 2; ++mt) {
        const int f0 = wb + mt * 16 + quad * 4;
        avc[mt] = *(const f32x4*)&Atab[f0];
        evc[mt] = *(const f32x4*)&Etab[f0];
    }
    float ctc = ctab[0];
    #pragma unroll
    for (int mt = 0; mt < 2; ++mt) {
        unsigned dw = 0;
        #pragma unroll
        for (int r = 0; r < 4; ++r) {
            const float v = fmaxf(fmaf(avc[mt][r], 0.5f, evc[mt][r]), 0.0f);
            dw |= ((unsigned)v) << (8 * r);
        }
        *(unsigned*)&sStage[4096 + wr[mt]]  = dw;   // sCA
        *(unsigned*)&sStage[12288 + wr[mt]] = dw;   // sCB
    }
    __syncthreads();
    {
        const float f2 = ctc * sWc127;
        i32x4 a2A[2] = {}, a2B[2] = {};
        gemm(4096, WC, a2A);
        gemm(12288, WC, a2B);
        #pragma unroll
        for (int mt = 0; mt < 2; ++mt) {
            const int f0 = wb + mt * 16 + quad * 4;
            const f32x4 cA = *(const f32x4*)&cue[(row0 + L) * 256 + f0];
            const f32x4 cB = *(const f32x4*)&cue[(row0 + 16 + L) * 256 + f0];
            unsigned dwA = 0, dwB = 0;
            #pragma unroll
            for (int r = 0; r < 4; ++r) {
                const float n5A = __builtin_amdgcn_fmed3f(fmaf((float)a2A[mt][r], f2, e5A[mt][r]), 0.0f, 1.0f);
                const float n5B = __builtin_amdgcn_fmed3f(fmaf((float)a2B[mt][r], f2, e5B[mt][r]), 0.0f, 1.0f);
                const float n3A = __builtin_amdgcn_fmed3f(cA[r], 0.0f, 1.0f);   // ec3_prev=0
                const float n3B = __builtin_amdgcn_fmed3f(cB[r], 0.0f, 1.0f);
                e5A[mt][r] = n5A; e3A[mt][r] = n3A;
                e5B[mt][r] = n5B; e3B[mt][r] = n3B;
                dwA |= ((unsigned)fmaf(n3A, 127.0f, 0.5f)) << (8 * r);
                dwB |= ((unsigned)fmaf(n3B, 127.0f, 0.5f)) << (8 * r);
            }
            *(unsigned*)&sStage[0 + wr[mt]]    = dwA;   // sEA
            *(unsigned*)&sStage[8192 + wr[mt]] = dwB;   // sEB
        }
    }
    __syncthreads();

    // tables for t=1; prime G1_A(t=1)
    #pragma unroll
    for (int mt = 0; mt < 2; ++mt) {
        const int f0 = 256 + wb + mt * 16 + quad * 4;
        avc[mt] = *(const f32x4*)&Atab[f0];
        evc[mt] = *(const f32x4*)&Etab[f0];
    }
    ctc = ctab[1];
    i32x4 acc1A[2] = {};
    gemm(0, WA, acc1A);

    // ===== steady state t = 1..98: 4 staggered phases, 4 barriers =====
    for (int t = 1; t <= 98; ++t) {
        f32x4 avn[2], evn[2];   // prefetch t+1 tables (hide global latency)
        #pragma unroll
        for (int mt = 0; mt < 2; ++mt) {
            const int f0 = (t + 1) * 256 + wb + mt * 16 + quad * 4;
            avn[mt] = *(const f32x4*)&Atab[f0];
            evn[mt] = *(const f32x4*)&Etab[f0];
        }
        const float ctn = ctab[t + 1];
        const float f2 = ctc * sWc127;

        i32x4 acc1B[2] = {};   // P1: G1_B | e1_A
        if (wlow) { gemm(8192, WA, acc1B); e1(acc1A, avc, evc, 4096); }
        else      { e1(acc1A, avc, evc, 4096); gemm(8192, WA, acc1B); }
        __syncthreads();

        i32x4 acc2A[2] = {};   // P2: G2_A | e1_B
        if (wlow) { gemm(4096, WC, acc2A); e1(acc1B, avc, evc, 12288); }
        else      { e1(acc1B, avc, evc, 12288); gemm(4096, WC, acc2A); }
        __syncthreads();

        i32x4 acc2B[2] = {};   // P3: G2_B | e2_A
        if (wlow) { gemm(12288, WC, acc2B); e2(acc2A, e5A, e3A, 0, f2); }
        else      { e2(acc2A, e5A, e3A, 0, f2); gemm(12288, WC, acc2B); }
        __syncthreads();

        acc1A[0] = i32x4{}; acc1A[1] = i32x4{};   // P4: G1_A(t+1) | e2_B
        if (wlow) { gemm(0, WA, acc1A); e2(acc2B, e5B, e3B, 8192, f2); }
        else      { e2(acc2B, e5B, e3B, 8192, f2); gemm(0, WA, acc1A); }
        __syncthreads();

        #pragma unroll
        for (int mt = 0; mt < 2; ++mt) { avc[mt] = avn[mt]; evc[mt] = evn[mt]; }
        ctc = ctn;
    }

    // ===== t = 99 (peeled): ca1 only -> out = ca1 @ Waction =====
    {
        i32x4 acc1B[2] = {};
        gemm(8192, WA, acc1B);
        float pA0 = 0.f, pA1 = 0.f, pB0 = 0.f, pB1 = 0.f;
        #pragma unroll
        for (int mt = 0; mt < 2; ++mt) {
            const int f0 = wb + mt * 16 + quad * 4;
            const f32x4 w0 = *(const f32x4*)&Wact[f0 * 2];       // feats f0,f0+1
            const f32x4 w1 = *(const f32x4*)&Wact[f0 * 2 + 4];   // feats f0+2,f0+3
            #pragma unroll
            for (int r = 0; r < 4; ++r) {
                const float sA = __builtin_amdgcn_rcpf(1.0f + __expf((float)acc1A[mt][r] * nf1));
                const float sB = __builtin_amdgcn_rcpf(1.0f + __expf((float)acc1B[mt][r] * nf1));
                const float cAv = fmaxf(fmaf(avc[mt][r], sA, evc[mt][r]) - 0.5f, 0.0f) * ctc;
                const float cBv = fmaxf(fmaf(avc[mt][r], sB, evc[mt][r]) - 0.5f, 0.0f) * ctc;
                const float wa  = (r & 2) ? ((r & 1) ? w1[2] : w1[0]) : ((r & 1) ? w0[2] : w0[0]);
                const float wbv = (r & 2) ? ((r & 1) ? w1[3] : w1[1]) : ((r & 1) ? w0[3] : w0[1]);
                pA0 = fmaf(cAv, wa, pA0); pA1 = fmaf(cAv, wbv, pA1);
                pB0 = fmaf(cBv, wa, pB0); pB1 = fmaf(cBv, wbv, pB1);
            }
        }
        pA0 += __shfl_xor(pA0, 16); pA0 += __shfl_xor(pA0, 32);
        pA1 += __shfl_xor(pA1, 16); pA1 += __shfl_xor(pA1, 32);
        pB0 += __shfl_xor(pB0, 16); pB0 += __shfl_xor(pB0, 32);
        pB1 += __shfl_xor(pB1, 16); pB1 += __shfl_xor(pB1, 32);
        if (quad == 0) {
            sPart[((0 * 16 + L) * 2 + 0) * 8 + wave] = pA0;
            sPart[((0 * 16 + L) * 2 + 1) * 8 + wave] = pA1;
            sPart[((1 * 16 + L) * 2 + 0) * 8 + wave] = pB0;
            sPart[((1 * 16 + L) * 2 + 1) * 8 + wave] = pB1;
        }
    }
    __syncthreads();
    if (tid < 64) {
        float s = 0.f;
        #pragma unroll
        for (int g = 0; g < 8; ++g) s += sPart[tid * 8 + g];
        out[(row0 + (tid >> 1)) * 2 + (tid & 1)] = s;
    }
}

extern "C" void kernel_launch(void* const* d_in, const int* in_sizes, int n_in,
                              void* d_out, int out_size, void* d_ws, size_t ws_size,
                              hipStream_t stream) {
    const float* cue      = (const float*)d_in[0];
    const float* ec5_init = (const float*)d_in[1];
    const float* Wapical  = (const float*)d_in[2];
    const float* Wbasal   = (const float*)d_in[3];
    const float* Wca1ec5  = (const float*)d_in[4];
    const float* Waction  = (const float*)d_in[5];
    const float* ca1bias  = (const float*)d_in[6];
    float* out = (float*)d_out;

    float* Atab = (float*)d_ws;                  // 25600 f32
    float* Etab = Atab + 25600;                  // 25600 f32
    float* ctab = Etab + 25600;                  // 100 f32  (ends at float 51300 -> 16B aligned)
    int*   scaleWS = (int*)(ctab + 100);         // 4 ints (2 used + pad)
    char*  qWap = (char*)(scaleWS + 4);          // 65536 B, 16B aligned
    char*  qWc  = qWap + 65536;                  // 65536 B   (total ~336 KB)

    basal2_kernel<<<100, 256, 0, stream>>>(Wbasal, ca1bias, Atab, Etab, ctab, scaleWS);
    wmax_kernel<<<256, 256, 0, stream>>>(Wapical, Wca1ec5, scaleWS);
    wquant_kernel<<<256, 256, 0, stream>>>(Wapical, Wca1ec5, scaleWS, qWap, qWc);
    rnn_kernel<<<1024, 512, 0, stream>>>(cue, ec5_init, qWap, qWc, scaleWS, Waction,
                                         Atab, Etab, ctab, out);
}

// Round 6
// 622.618 us; speedup vs baseline: 1.4717x; 1.4717x over previous
//
#include <hip/hip_runtime.h>

// HPCrnn R6: force 2-blocks/CU residency. Diagnosis: all prior rounds ran at
// ~23% occupancy = 1 block/CU (VGPR+AGPR unified file > 128/wave), so barrier
// drains and LDS/MFMA latency had no co-resident block to hide behind.
// Fix: 16-row blocks (single tile), persistent regs ~115 (weights i8 64 +
// state 16 + misc), __launch_bounds__(512,4) enforces <=128 => 16 waves/CU.
// Numerics identical to R4/R5 (i8 16x16x64 MFMA, validated absmax 9.8e-4).

typedef int   i32x4 __attribute__((ext_vector_type(4)));
typedef float f32x4 __attribute__((ext_vector_type(4)));

// ---------- pre 1: basal tables + zero scale slots ----------
__global__ void basal2_kernel(const float* __restrict__ Wbasal,
                              const float* __restrict__ bias,
                              float* __restrict__ Atab, float* __restrict__ Etab,
                              float* __restrict__ ctab, int* __restrict__ scaleWS) {
    const int t = blockIdx.x, n = threadIdx.x;
    __shared__ float ca3s[256], red[256];
    const float x = (float)(t + 1);
    const float c0 = (float)n * (100.0f / 255.0f);
    const float d = (x - c0) * 0.2f;
    ca3s[n] = expf(-0.5f * d * d);
    __syncthreads();
    float bas = 0.f;
    #pragma unroll 8
    for (int k = 0; k < 256; ++k) bas += ca3s[k] * Wbasal[k * 256 + n];
    red[n] = bas;
    __syncthreads();
    for (int s = 128; s > 0; s >>= 1) {
        if (n < s) red[n] = fmaxf(red[n], red[n + s]);
        __syncthreads();
    }
    const float bmax = red[0];
    const float cq = 126.0f / (2.0f * bmax);   // headroom so q(ca1) < 127.5
    Atab[t * 256 + n] = bas * cq;
    Etab[t * 256 + n] = (bas - bias[n]) * cq + 0.5f;   // +0.5 folds rounding
    if (n == 0) ctab[t] = (2.0f * bmax) / 126.0f;
    if (t == 0 && n < 2) scaleWS[n] = 0;
}

// ---------- pre 2: weight absmax ----------
__global__ void wmax_kernel(const float* __restrict__ Wap, const float* __restrict__ Wc,
                            int* __restrict__ scaleWS) {
    const int i = blockIdx.x * 256 + threadIdx.x;
    float m1 = fabsf(Wap[i]);
    float m2 = fabsf(Wc[i]);
    #pragma unroll
    for (int o = 1; o < 64; o <<= 1) {
        m1 = fmaxf(m1, __shfl_xor(m1, o));
        m2 = fmaxf(m2, __shfl_xor(m2, o));
    }
    __shared__ float r1[4], r2[4];
    const int wv = threadIdx.x >> 6, ln = threadIdx.x & 63;
    if (ln == 0) { r1[wv] = m1; r2[wv] = m2; }
    __syncthreads();
    if (threadIdx.x == 0) {
        const float a = fmaxf(fmaxf(r1[0], r1[1]), fmaxf(r1[2], r1[3]));
        const float b = fmaxf(fmaxf(r2[0], r2[1]), fmaxf(r2[2], r2[3]));
        atomicMax(&scaleWS[0], __float_as_int(a));
        atomicMax(&scaleWS[1], __float_as_int(b));
    }
}

// ---------- pre 3: quantize weights to i8, transposed to [m][k] ----------
__global__ void wquant_kernel(const float* __restrict__ Wap, const float* __restrict__ Wc,
                              const int* __restrict__ scaleWS,
                              char* __restrict__ qWap, char* __restrict__ qWc) {
    const int m = blockIdx.x, k = threadIdx.x;
    const float q1 = 127.0f / __int_as_float(scaleWS[0]);
    const float q2 = 127.0f / __int_as_float(scaleWS[1]);
    qWap[m * 256 + k] = (char)(int)rintf(Wap[k * 256 + m] * q1);
    qWc[m * 256 + k]  = (char)(int)rintf(Wc[k * 256 + m] * q2);
}

// ---------- main: 16 rows/block, 8 waves, 2 barriers/step, 2 blocks/CU ----------
__global__ __launch_bounds__(512, 4) void rnn_kernel(
    const float* __restrict__ cue, const float* __restrict__ ec5_init,
    const char* __restrict__ qWap, const char* __restrict__ qWc,
    const int* __restrict__ scaleWS, const float* __restrict__ Wact,
    const float* __restrict__ Atab, const float* __restrict__ Etab,
    const float* __restrict__ ctab, float* __restrict__ out)
{
    __shared__ __align__(16) char sStage[8192 + 1024];  // sE@0, sC@4096, sPart@8192
    float* sPart = (float*)&sStage[8192];               // [L][a][wave] = 16*2*8

    const int tid  = threadIdx.x;
    const int wave = tid >> 6;
    const int lane = tid & 63;
    const int quad = lane >> 4;
    const int L    = lane & 15;
    const int wb   = wave * 32;          // this wave's 32-feature slice
    const int row0 = blockIdx.x * 16;    // lane's batch row = row0 + L

    const float sW1 = __int_as_float(scaleWS[0]);
    const float sW2 = __int_as_float(scaleWS[1]);
    const float nf1 = -sW1 / (127.0f * 127.0f);   // gemm1 dequant (ec3 scale 127)
    const float sWc127 = sW2 / 127.0f;

    // weight A-frags: lane (quad,L) holds W^T[m=wb+mt*16+L][k=c*64+quad*16+j]
    i32x4 WA[2][4], WC[2][4];
    #pragma unroll
    for (int mt = 0; mt < 2; ++mt) {
        const int m = wb + mt * 16 + L;
        #pragma unroll
        for (int c = 0; c < 4; ++c) {
            WA[mt][c] = *(const i32x4*)&qWap[m * 256 + c * 64 + quad * 16];
            WC[mt][c] = *(const i32x4*)&qWc[m * 256 + c * 64 + quad * 16];
        }
    }

    // state fp32 (C/D layout): lane (quad,L) holds row row0+L, feats wb+mt*16+quad*4+r
    float e5[2][4], e3[2][4];
    #pragma unroll
    for (int mt = 0; mt < 2; ++mt) {
        const f32x4 a = *(const f32x4*)&ec5_init[(row0 + L) * 256 + wb + mt * 16 + quad * 4];
        #pragma unroll
        for (int r = 0; r < 4; ++r) { e5[mt][r] = a[r]; e3[mt][r] = 0.f; }
    }

    // XOR-swizzled stage addresses (16B blocks xor'd with row L): 2-way max conflicts
    int rd[4], wr[2];
    #pragma unroll
    for (int c = 0; c < 4; ++c)
        rd[c] = L * 256 + (((4 * c + quad) ^ L) << 4);
    #pragma unroll
    for (int mt = 0; mt < 2; ++mt)
        wr[mt] = L * 256 + (((wave * 2 + mt) ^ L) << 4) + quad * 4;

    auto gemm = [&](int sb, const i32x4 (&W)[2][4], i32x4 (&acc)[2]) {
        #pragma unroll
        for (int c = 0; c < 4; ++c) {
            const i32x4 bf = *(const i32x4*)&sStage[sb + rd[c]];
            acc[0] = __builtin_amdgcn_mfma_i32_16x16x64_i8(W[0][c], bf, acc[0], 0, 0, 0);
            acc[1] = __builtin_amdgcn_mfma_i32_16x16x64_i8(W[1][c], bf, acc[1], 0, 0, 0);
        }
    };

    // ===== t = 0 (peeled): ec3=0 -> sigmoid = 0.5 exactly; ca1 row-independent =====
    {
        #pragma unroll
        for (int mt = 0; mt < 2; ++mt) {
            const int f0 = wb + mt * 16 + quad * 4;
            const f32x4 av = *(const f32x4*)&Atab[f0];
            const f32x4 ev = *(const f32x4*)&Etab[f0];
            unsigned dw = 0;
            #pragma unroll
            for (int r = 0; r < 4; ++r) {
                const float v = fmaxf(fmaf(av[r], 0.5f, ev[r]), 0.0f);
                dw |= ((unsigned)v) << (8 * r);
            }
            *(unsigned*)&sStage[4096 + wr[mt]] = dw;   // q(ca1_0)
        }
        __syncthreads();
        const float f2 = ctab[0] * sWc127;
        i32x4 acc2[2] = {};
        gemm(4096, WC, acc2);
        #pragma unroll
        for (int mt = 0; mt < 2; ++mt) {
            const f32x4 cv = *(const f32x4*)&cue[(row0 + L) * 256 + wb + mt * 16 + quad * 4];
            unsigned dw = 0;
            #pragma unroll
            for (int r = 0; r < 4; ++r) {
                const float n5 = __builtin_amdgcn_fmed3f(
                    fmaf((float)acc2[mt][r], f2, e5[mt][r]), 0.0f, 1.0f);
                const float n3 = __builtin_amdgcn_fmed3f(cv[r], 0.0f, 1.0f);  // ec3_prev=0
                e5[mt][r] = n5; e3[mt][r] = n3;
                dw |= ((unsigned)fmaf(n3, 127.0f, 0.5f)) << (8 * r);
            }
            *(unsigned*)&sStage[wr[mt]] = dw;   // q(ec3)
        }
        __syncthreads();
    }

    // ===== steady state t = 1..98: 2 phases, 2 barriers =====
    for (int t = 1; t <= 98; ++t) {
        // per-step tables (uniform-per-lane loads; latency hidden by co-resident block)
        f32x4 avc[2], evc[2];
        #pragma unroll
        for (int mt = 0; mt < 2; ++mt) {
            const int f0 = t * 256 + wb + mt * 16 + quad * 4;
            avc[mt] = *(const f32x4*)&Atab[f0];
            evc[mt] = *(const f32x4*)&Etab[f0];
        }
        const float f2 = ctab[t] * sWc127;

        // Phase A: G1 (sE -> acc) + e1 (-> sC)
        i32x4 acc[2] = {};
        gemm(0, WA, acc);
        #pragma unroll
        for (int mt = 0; mt < 2; ++mt) {
            unsigned dw = 0;
            #pragma unroll
            for (int r = 0; r < 4; ++r) {
                const float s = __builtin_amdgcn_rcpf(1.0f + __expf((float)acc[mt][r] * nf1));
                const float v = fmaxf(fmaf(avc[mt][r], s, evc[mt][r]), 0.0f);
                dw |= ((unsigned)v) << (8 * r);
            }
            *(unsigned*)&sStage[4096 + wr[mt]] = dw;
        }
        __syncthreads();

        // Phase B: G2 (sC -> acc2) + e2 (-> sE, state update)
        i32x4 acc2[2] = {};
        gemm(4096, WC, acc2);
        #pragma unroll
        for (int mt = 0; mt < 2; ++mt) {
            unsigned dw = 0;
            #pragma unroll
            for (int r = 0; r < 4; ++r) {
                const float n5 = __builtin_amdgcn_fmed3f(
                    fmaf((float)acc2[mt][r], f2, e5[mt][r]), 0.0f, 1.0f);
                const float n3 = n5 * e3[mt][r];   // both in [0,1]: clip redundant
                e5[mt][r] = n5; e3[mt][r] = n3;
                dw |= ((unsigned)fmaf(n3, 127.0f, 0.5f)) << (8 * r);
            }
            *(unsigned*)&sStage[wr[mt]] = dw;
        }
        __syncthreads();
    }

    // ===== t = 99 (peeled): G1 + e1 + Waction partial dot =====
    {
        i32x4 acc[2] = {};
        gemm(0, WA, acc);
        const float ct = ctab[99];
        float p0 = 0.f, p1 = 0.f;
        #pragma unroll
        for (int mt = 0; mt < 2; ++mt) {
            const int f0 = wb + mt * 16 + quad * 4;
            const f32x4 av = *(const f32x4*)&Atab[99 * 256 + f0];
            const f32x4 ev = *(const f32x4*)&Etab[99 * 256 + f0];
            const f32x4 w0 = *(const f32x4*)&Wact[f0 * 2];       // feats f0, f0+1
            const f32x4 w1 = *(const f32x4*)&Wact[f0 * 2 + 4];   // feats f0+2, f0+3
            #pragma unroll
            for (int r = 0; r < 4; ++r) {
                const float s = __builtin_amdgcn_rcpf(1.0f + __expf((float)acc[mt][r] * nf1));
                const float c = fmaxf(fmaf(av[r], s, ev[r]) - 0.5f, 0.0f) * ct;
                const float wa = (r & 2) ? ((r & 1) ? w1[2] : w1[0]) : ((r & 1) ? w0[2] : w0[0]);
                const float wb2 = (r & 2) ? ((r & 1) ? w1[3] : w1[1]) : ((r & 1) ? w0[3] : w0[1]);
                p0 = fmaf(c, wa, p0);
                p1 = fmaf(c, wb2, p1);
            }
        }
        p0 += __shfl_xor(p0, 16); p0 += __shfl_xor(p0, 32);
        p1 += __shfl_xor(p1, 16); p1 += __shfl_xor(p1, 32);
        if (quad == 0) {
            sPart[(L * 2 + 0) * 8 + wave] = p0;
            sPart[(L * 2 + 1) * 8 + wave] = p1;
        }
    }
    __syncthreads();
    if (tid < 32) {
        float s = 0.f;
        #pragma unroll
        for (int g = 0; g < 8; ++g) s += sPart[tid * 8 + g];
        out[row0 * 2 + tid] = s;
    }
}

extern "C" void kernel_launch(void* const* d_in, const int* in_sizes, int n_in,
                              void* d_out, int out_size, void* d_ws, size_t ws_size,
                              hipStream_t stream) {
    const float* cue      = (const float*)d_in[0];
    const float* ec5_init = (const float*)d_in[1];
    const float* Wapical  = (const float*)d_in[2];
    const float* Wbasal   = (const float*)d_in[3];
    const float* Wca1ec5  = (const float*)d_in[4];
    const float* Waction  = (const float*)d_in[5];
    const float* ca1bias  = (const float*)d_in[6];
    float* out = (float*)d_out;

    float* Atab = (float*)d_ws;                  // 25600 f32
    float* Etab = Atab + 25600;                  // 25600 f32
    float* ctab = Etab + 25600;                  // 100 f32
    int*   scaleWS = (int*)(ctab + 100);         // 4 ints
    char*  qWap = (char*)(scaleWS + 4);          // 65536 B
    char*  qWc  = qWap + 65536;                  // 65536 B

    basal2_kernel<<<100, 256, 0, stream>>>(Wbasal, ca1bias, Atab, Etab, ctab, scaleWS);
    wmax_kernel<<<256, 256, 0, stream>>>(Wapical, Wca1ec5, scaleWS);
    wquant_kernel<<<256, 256, 0, stream>>>(Wapical, Wca1ec5, scaleWS, qWap, qWc);
    rnn_kernel<<<2048, 512, 0, stream>>>(cue, ec5_init, qWap, qWc, scaleWS, Waction,
                                         Atab, Etab, ctab, out);
}